// Round 2
// baseline (193.513 us; speedup 1.0000x reference)
//
#include <hip/hip_runtime.h>
#include <math.h>

// PeakAreaFloodLoss: B=2048 rows, S=8192 cols, fp32 p/t + i32 mask -> scalar.
// One block per row, 512 threads, 16 elems/thread. Single HBM sweep; the
// t_peak-dependent second pass runs from per-thread REGISTER staging
// (statically indexed, fully unrolled -> no scratch), not LDS, so occupancy
// is VGPR-bound (~6-8 waves/SIMD) instead of LDS-bound (2 waves/SIMD).

#define S_LEN 8192
#define BLK   512
#define NWAVE (BLK / 64)
#define VEC   (S_LEN / 4 / BLK)   // 4 float4 per thread = 16 elements

__device__ __forceinline__ float waveSum(float x) {
    #pragma unroll
    for (int o = 32; o > 0; o >>= 1) x += __shfl_down(x, o, 64);
    return x;
}
__device__ __forceinline__ float waveMax(float x) {
    #pragma unroll
    for (int o = 32; o > 0; o >>= 1) x = fmaxf(x, __shfl_down(x, o, 64));
    return x;
}

__global__ __launch_bounds__(BLK) void flood_loss_kernel(
    const float* __restrict__ P, const float* __restrict__ T,
    const int* __restrict__ M, float* __restrict__ out, float invB)
{
    __shared__ float red[NWAVE][4]; // cross-wave reduction scratch (128 B)

    const int tid  = threadIdx.x;
    const int wid  = tid >> 6;
    const int lane = tid & 63;
    const size_t base = (size_t)blockIdx.x * S_LEN;

    const float4* __restrict__ P4 = (const float4*)(P + base);
    const float4* __restrict__ T4 = (const float4*)(T + base);
    const int4*   __restrict__ M4 = (const int4*)(M + base);

    // ---- pass 1: one coalesced HBM sweep; stats + register staging ----
    float tenc[VEC * 4]; // t, invalid -> -INF (one-compare 'high' test)
    float d2v [VEC * 4]; // valid ? (p-t)^2 : 0
    float ssq = 0.f, fn = 0.f;
    float tpk = -INFINITY, ppk = -INFINITY;

    #pragma unroll
    for (int it = 0; it < VEC; ++it) {
        const int v = it * BLK + tid;      // float4 index, coalesced
        float4 p4 = P4[v];
        float4 t4 = T4[v];
        int4   m4 = M4[v];
        float pe[4] = {p4.x, p4.y, p4.z, p4.w};
        float te[4] = {t4.x, t4.y, t4.z, t4.w};
        int   me[4] = {m4.x, m4.y, m4.z, m4.w};
        #pragma unroll
        for (int j = 0; j < 4; ++j) {
            // valid = mask && !isnan(p) && !isnan(t)   (x!=x is the NaN test)
            bool valid = (me[j] != 0) && !(pe[j] != pe[j]) && !(te[j] != te[j]);
            float d  = pe[j] - te[j];
            float d2 = valid ? d * d : 0.f;
            ssq += d2;
            fn  += valid ? 1.f : 0.f;
            if (valid) { tpk = fmaxf(tpk, te[j]); ppk = fmaxf(ppk, pe[j]); }
            tenc[it * 4 + j] = valid ? te[j] : -INFINITY; // static index
            d2v [it * 4 + j] = d2;
        }
    }

    ssq = waveSum(ssq); fn = waveSum(fn);
    tpk = waveMax(tpk); ppk = waveMax(ppk);
    if (lane == 0) { red[wid][0] = fn; red[wid][1] = ssq; red[wid][2] = tpk; red[wid][3] = ppk; }
    __syncthreads();

    // every thread needs tpk for pass 2; serial 8-way reduce is cheap
    float fnT = 0.f, ssqT = 0.f, tpkT = -INFINITY, ppkT = -INFINITY;
    #pragma unroll
    for (int w = 0; w < NWAVE; ++w) {
        fnT  += red[w][0];
        ssqT += red[w][1];
        tpkT  = fmaxf(tpkT, red[w][2]);
        ppkT  = fmaxf(ppkT, red[w][3]);
    }

    // ---- pass 2: high subset, from registers ----
    // ref: high = valid & (t_peak<=0 ? true : t >= 0.8*t_peak)
    // tenc = -INF for invalid, so both branches are one float compare.
    const bool  tpos = tpkT > 0.f;
    const float thr  = tpkT * 0.8f;
    float nh = 0.f, ssqh = 0.f;
    #pragma unroll
    for (int k = 0; k < VEC * 4; ++k) {
        bool hi = tpos ? (tenc[k] >= thr) : (tenc[k] > -INFINITY);
        nh   += hi ? 1.f : 0.f;
        ssqh += hi ? d2v[k] : 0.f;
    }
    nh = waveSum(nh); ssqh = waveSum(ssqh);
    __syncthreads(); // all reads of red (pass-1 partials) done before reuse
    if (lane == 0) { red[wid][0] = nh; red[wid][1] = ssqh; }
    __syncthreads();

    if (tid == 0) {
        float nht = 0.f, ssqht = 0.f;
        #pragma unroll
        for (int w = 0; w < NWAVE; ++w) { nht += red[w][0]; ssqht += red[w][1]; }
        float overall = (fnT > 0.f) ? sqrtf(ssqT  / fmaxf(fnT, 1.f)) : 0.f;
        float high_r  = (nht > 0.f) ? sqrtf(ssqht / fmaxf(nht, 1.f)) : 0.f;
        float peak_e  = (fnT > 0.f) ? fabsf(ppkT - tpkT) : 0.f;
        float loss = 0.5f * overall + 2.0f * peak_e + 1.0f * high_r;
        atomicAdd(out, loss * invB);
    }
}

extern "C" void kernel_launch(void* const* d_in, const int* in_sizes, int n_in,
                              void* d_out, int out_size, void* d_ws, size_t ws_size,
                              hipStream_t stream) {
    const float* P = (const float*)d_in[0];
    const float* T = (const float*)d_in[1];
    const int*   M = (const int*)d_in[2];
    float* out = (float*)d_out;
    const int B = in_sizes[0] / S_LEN; // 2048

    // d_out is re-poisoned to 0xAA before every timed call; zero it on-stream.
    hipMemsetAsync(out, 0, sizeof(float), stream);
    flood_loss_kernel<<<B, BLK, 0, stream>>>(P, T, M, out, 1.0f / (float)B);
}